// Round 5
// baseline (89.282 us; speedup 1.0000x reference)
//
#include <hip/hip_runtime.h>

// BKT forward scan — faithful fp32 K-space recurrence, latency-optimized.
//
// Reference semantics must be replicated to fp32 BIT-exactness: the
// recurrence has an absorbing state (K==1.0f, reached after ~14 consecutive
// correct answers; absorbing under BOTH branches), and near it a 1-ulp
// deviation amplifies x6.3/step up to absmax 0.88. So: reference op order,
// IEEE correctly-rounded ops only, no contraction, no algebraic rewrites.
//   kc = K*(1-s) / (K*(1-s) + g*(1-K))      (rt==1)
//   kw = K*s     / (K*s     + (1-K)*(1-g))  (rt==0)
//   K' = k + (1-k)*p
//
// R5 vs R4: prefetch depth 1 -> 4 int4-chunks (16 steps ~ >1100 cy of cover
// vs ~900 cy uncoalesced-load miss latency). R4's counters showed 160 cy/step
// = ~95 cy chain + ~65 cy exposed vmcnt stall; this removes the stall.
// Static register rotation (buf0..buf3), no runtime-indexed arrays.

static constexpr int BROWS = 8192;
static constexpr int LCOLS = 1024;
static constexpr int LM1   = 1023;

// Correctly-rounded u/d for normal, well-scaled operands:
// rcp (<=1ulp) -> 2x Newton (y converges to the correctly-rounded
// reciprocal) -> Markstein fma-correction => IEEE RN quotient.
// Verified bit-exact vs np reference (absmax 0.0 in R3/R4).
__device__ __forceinline__ float fdiv_cr(float u, float d) {
    float y = __builtin_amdgcn_rcpf(d);
    y = __fmaf_rn(__fmaf_rn(-d, y, 1.0f), y, y);
    y = __fmaf_rn(__fmaf_rn(-d, y, 1.0f), y, y);
    float q = __fmul_rn(u, y);
    float r = __fmaf_rn(-d, q, u);
    return __fmaf_rn(r, y, q);
}

__device__ __forceinline__ float bkt_step(float K, int rt,
                                          float s_, float g_,
                                          float cs, float cg, float p_) {
    const float omK = __fsub_rn(1.0f, K);
    const float A   = (rt == 1) ? cs : s_;   // multiplier on K
    const float Bc  = (rt == 1) ? g_ : cg;   // multiplier on (1-K)
    const float num = __fmul_rn(K, A);
    const float den = __fadd_rn(num, __fmul_rn(Bc, omK));
    const float k   = fdiv_cr(num, den);
    return __fadd_rn(k, __fmul_rn(__fsub_rn(1.0f, k), p_));
}

__global__ __launch_bounds__(64) void bkt_scan_kernel(
    const int*   __restrict__ resp,
    const float* __restrict__ p_slip,
    const float* __restrict__ p_guess,
    const float* __restrict__ p_train,
    const float* __restrict__ p_learn,
    float*       __restrict__ out)   // [pred (B*LM1) | r_shft (B*LM1)]
{
    const int b = blockIdx.x * 64 + threadIdx.x;   // one row per thread

    const float s_ = *p_slip;
    const float g_ = *p_guess;
    const float p_ = *p_train;
    float       K  = *p_learn;
    const float cs = __fsub_rn(1.0f, s_);
    const float cg = __fsub_rn(1.0f, g_);

    const int4* row  = reinterpret_cast<const int4*>(resp + (size_t)b * LCOLS);
    float*      pred = out + (size_t)b * LM1;
    float*      rs   = out + (size_t)BROWS * LM1 + (size_t)b * LM1;

    // 4-deep prefetch pipeline, statically rotated.
    int4 buf0 = row[0];
    int4 buf1 = row[1];
    int4 buf2 = row[2];
    int4 buf3 = row[3];

#define BKT_PROCESS(V, J)                                                  \
    {                                                                      \
        const int t0 = 4 * (J);                                            \
        if ((J) > 0) rs[t0 - 1] = (float)(V).x;                            \
        rs[t0]     = (float)(V).y;                                         \
        rs[t0 + 1] = (float)(V).z;                                         \
        rs[t0 + 2] = (float)(V).w;                                         \
        K = bkt_step(K, (V).x, s_, g_, cs, cg, p_);  pred[t0]     = K;     \
        K = bkt_step(K, (V).y, s_, g_, cs, cg, p_);  pred[t0 + 1] = K;     \
        K = bkt_step(K, (V).z, s_, g_, cs, cg, p_);  pred[t0 + 2] = K;     \
        if ((J) < LCOLS / 4 - 1) {                                         \
            K = bkt_step(K, (V).w, s_, g_, cs, cg, p_);  pred[t0 + 3] = K; \
        }                                                                  \
    }

    for (int jj = 0; jj < LCOLS / 4; jj += 4) {
        // consume buf_k (chunk jj+k), immediately re-issue its replacement
        // (chunk jj+4+k, clamped in-bounds; redundant tail reloads are L1
        // hits). Replacement is next consumed 16 steps later (>1100 cy).
        const int j0 = jj, j1 = jj + 1, j2 = jj + 2, j3 = jj + 3;
        const int n0 = (jj + 4 < 256) ? jj + 4 : 255;
        const int n1 = (jj + 5 < 256) ? jj + 5 : 255;
        const int n2 = (jj + 6 < 256) ? jj + 6 : 255;
        const int n3 = (jj + 7 < 256) ? jj + 7 : 255;

        BKT_PROCESS(buf0, j0);  buf0 = row[n0];
        BKT_PROCESS(buf1, j1);  buf1 = row[n1];
        BKT_PROCESS(buf2, j2);  buf2 = row[n2];
        BKT_PROCESS(buf3, j3);  buf3 = row[n3];
    }
#undef BKT_PROCESS
}

extern "C" void kernel_launch(void* const* d_in, const int* in_sizes, int n_in,
                              void* d_out, int out_size, void* d_ws, size_t ws_size,
                              hipStream_t stream) {
    const int*   resp = (const int*)  d_in[0];
    const float* s    = (const float*)d_in[1];
    const float* g    = (const float*)d_in[2];
    const float* tp   = (const float*)d_in[3];
    const float* lp   = (const float*)d_in[4];
    float* out = (float*)d_out;

    bkt_scan_kernel<<<BROWS / 64, 64, 0, stream>>>(resp, s, g, tp, lp, out);
}